// Round 7
// baseline (138.902 us; speedup 1.0000x reference)
//
#include <hip/hip_runtime.h>
#include <stdint.h>

// CropConv implicit GEMM (bf16 MFMA, fp32 accum).
//   M=64 (oc), K=576 (ic*3*3), N=262144 (b*h*w)
// v6: latency fix. v5 post-mortem: per-work latency invariant ~23us/2-row
// across v1/v2/v3/v5 regardless of structure; throughput = residency(~2.3)/
// latency. The chain: 18 K-groups each serially wait on 2 global A-loads
// (72KB table > 32KB L1 -> L2 ~250cyc each; 84 VGPR -> no deep pipelining).
//   - A-HOIST: all 36 weight fragments (144 VGPR) loaded in one burst BEFORE
//     staging (L2 latency hides under staging's HBM latency). K-loop becomes
//     pure ds_read_b128 + MFMA, statically indexed. launch_bounds(256,2).
//   - staging-write conflict fix: v5's 2.36M conflicts = 48 ds_write_b128 x
//     16-way (lane->col-quad mapping stepped slots by 4). Swap bits:
//     j = t&7 (octet varies per lane -> slots spread over all 8 groups),
//     c4 = t>>3. Same global coalescing (16 lines/instr), 0 write conflicts.
//   - unchanged from v5: 1h x 128w x 64oc block, LDS 3r x 130c (48.75 KiB),
//     full-row clean traffic (FETCH 33MB / WRITE 66MB measured), swizzle
//     slot = (j+c)&7, XCD remap, crop-mask epilogue.
// Weights: pre-pass -> bf16 workspace [kk][ch][i][lane] (72 KiB).
// Fallback: if ws_size < 73728, launch the v1 fully-fused kernel.

#define B_ 16
#define C_ 64
#define H_ 128
#define W_ 128

#define TCOLS_A 130
#define XLDS_A (3 * TCOLS_A * 8)      // 3120 uint4 = 48.75 KiB

typedef float f32x4 __attribute__((ext_vector_type(4)));
typedef short bf16x8 __attribute__((ext_vector_type(8)));

__device__ inline unsigned short f2bf(float f) {
    union { float f; uint32_t u; } v; v.f = f;
    uint32_t u = v.u + 0x7FFF + ((v.u >> 16) & 1);   // RNE
    return (unsigned short)(u >> 16);
}

// ---- pre-pass: weights [oc][ic][3][3] fp32 -> bf16 [kk][ch][i][lane][e] ----
// element L = (((kk*2+ch)*4 + i)*64 + lane)*8 + e  holds
//   wgt[oc = i*16 + (lane&15)][ic = ch*32 + (lane>>4)*8 + e][kk]
__global__ __launch_bounds__(256) void xform_weight(
    const float* __restrict__ wgt, uint16_t* __restrict__ Wb)
{
    int L = blockIdx.x * 256 + threadIdx.x;       // < 36864
    int e    = L & 7;
    int lane = (L >> 3) & 63;
    int i    = (L >> 9) & 3;
    int ch   = (L >> 11) & 1;
    int kk   = L >> 12;
    int oc   = i * 16 + (lane & 15);
    int ic   = ch * 32 + (lane >> 4) * 8 + e;
    Wb[L] = f2bf(wgt[((size_t)oc * 64 + ic) * 9 + kk]);
}

// ---- main: 1h x 128w x 64oc block, A in registers, K-loop = LDS+MFMA ----
// grid 2048 = 16 b x 128 ht; block 256 = 4 waves;
// wave wv: ohalf = wv&1 (oc 32*ohalf..+31), whalf = wv>>1 (w 64*whalf..+63).
// LDS tile: [r:3][c:130][slot:8] uint4, slot = (j + c) & 7, j = ic>>3.
// tile col c <-> global w = c - 1 (cols 0 and 129 = image w-pad, zeroed).
__global__ __launch_bounds__(256, 2) void conv_main(
    const uint4* __restrict__ Wq,    // [9][2][4][64] uint4 bf16
    const float* __restrict__ x,     // [16][64][128][128] fp32
    float* __restrict__ out)         // [16][64][128][128] fp32
{
    __shared__ uint4 lds[XLDS_A];    // 48.75 KiB

    const int t    = threadIdx.x;
    const int lane = t & 63;
    const int wv   = t >> 6;
    const int n    = lane & 15;
    const int q    = lane >> 4;

    // XCD-contiguous remap (2048 = 8 * 256, bijective)
    const int d    = blockIdx.x;
    const int orig = (d & 7) * 256 + (d >> 3);
    const int ht   = orig & 127;                  // output row
    const int b    = orig >> 7;

    const int ohalf = wv & 1;             // oc half
    const int wq    = (wv >> 1) * 64;     // w half base

    // ---- A-hoist: 36 fragments = 144 VGPR, one independent load burst.
    // group g = (kh*3+kw)*2 + ch; Areg[g][i] covers oc = ohalf*32 + i*16 + ...
    bf16x8 Areg[18][2];
    #pragma unroll
    for (int g = 0; g < 18; ++g)
        #pragma unroll
        for (int i = 0; i < 2; ++i)
            Areg[g][i] = __builtin_bit_cast(bf16x8,
                Wq[(g * 4 + ohalf * 2 + i) * 64 + lane]);

    // ---- stage input rows ht-1..ht+1, full width, fp32 -> swizzled bf16 ----
    // thread = (j: t&7 ic-octet) x (c4: t>>3 col-quad). j varies across lanes
    // -> ds_write slots spread over all 8 bank groups (v5 had 16-way conflict).
    {
        const int j     = t & 7;                  // ic octet 0..7
        const int c4    = t >> 3;                 // col-quad 0..31
        const int cbase = 1 + c4 * 4;             // tile col base (1..125)
        const int wg0   = c4 * 4;                 // global w base

        #pragma unroll
        for (int r = 0; r < 3; ++r) {
            const int h = ht - 1 + r;             // -1..128
            if (h < 0 || h >= H_) {               // image h-pad: zero row
                uint4 z; z.x = z.y = z.z = z.w = 0;
                #pragma unroll
                for (int cc = 0; cc < 4; ++cc)
                    lds[(r * TCOLS_A + cbase + cc) * 8 +
                        ((j + cbase + cc) & 7)] = z;
            } else {
                const float* src =
                    x + (((size_t)(b * C_ + j * 8)) * H_ + h) * W_ + wg0;
                f32x4 f[8];
                #pragma unroll
                for (int e = 0; e < 8; ++e)
                    f[e] = *(const f32x4*)(src + (size_t)e * (H_ * W_));
                #pragma unroll
                for (int cc = 0; cc < 4; ++cc) {
                    uint32_t u[4];
                    #pragma unroll
                    for (int p = 0; p < 4; ++p)
                        u[p] = (uint32_t)f2bf(f[2 * p][cc]) |
                               ((uint32_t)f2bf(f[2 * p + 1][cc]) << 16);
                    lds[(r * TCOLS_A + cbase + cc) * 8 +
                        ((j + cbase + cc) & 7)] = *(const uint4*)u;
                }
            }
        }
        // zero pad cols 0 and 129: 2 sides x 3 rows x 8 octets = 48 uint4
        if (t < 48) {
            const int ce = (t < 24) ? 0 : (TCOLS_A - 1);
            const int u  = (t < 24) ? t : t - 24;
            const int r  = u >> 3, jj = u & 7;
            uint4 z; z.x = z.y = z.z = z.w = 0;
            lds[(r * TCOLS_A + ce) * 8 + ((jj + ce) & 7)] = z;
        }
    }
    __syncthreads();

    // ---- K-loop: 18 groups, pure {4 ds_read_b128 + 8 MFMA}, A from regs ----
    f32x4 acc[2][4];
    #pragma unroll
    for (int i = 0; i < 2; ++i)
        #pragma unroll
        for (int f = 0; f < 4; ++f)
            acc[i][f] = (f32x4){0.f, 0.f, 0.f, 0.f};

    #pragma unroll
    for (int kh = 0; kh < 3; ++kh) {
        #pragma unroll
        for (int kw = 0; kw < 3; ++kw) {
            #pragma unroll
            for (int ch = 0; ch < 2; ++ch) {
                const int g = (kh * 3 + kw) * 2 + ch;     // compile-time
                bf16x8 bb[4];
                #pragma unroll
                for (int f = 0; f < 4; ++f) {
                    const int ct  = wq + f * 16 + n + kw;     // 0..129
                    const int idx = (kh * TCOLS_A + ct) * 8 +
                                    ((ch * 4 + q + ct) & 7);
                    bb[f] = __builtin_bit_cast(bf16x8, lds[idx]);
                }
                #pragma unroll
                for (int i = 0; i < 2; ++i)
                    #pragma unroll
                    for (int f = 0; f < 4; ++f)
                        acc[i][f] = __builtin_amdgcn_mfma_f32_16x16x32_bf16(
                            Areg[g][i], bb[f], acc[i][f], 0, 0, 0);
            }
        }
    }

    // ---- epilogue: oc = ohalf*32 + i*16 + q*4 + r, crop mask ----
    const int  h  = ht;
    const bool hz = (h >= 44 && h < 84);
    #pragma unroll
    for (int f = 0; f < 4; ++f) {
        const int w0 = wq + f * 16 + n;
        const bool zz = hz && (w0 >= 44 && w0 < 84);
        #pragma unroll
        for (int i = 0; i < 2; ++i) {
            #pragma unroll
            for (int r = 0; r < 4; ++r) {
                const int oc = ohalf * 32 + i * 16 + q * 4 + r;
                out[(((size_t)b * C_ + oc) * H_ + h) * W_ + w0] =
                    zz ? 0.f : acc[i][f][r];
            }
        }
    }
}

// ================= fallback: fully-fused single kernel (v1, 88.5 us) ========
#define WLDS_U4 4608   // 9*2*4*64 uint4 = 72 KiB weights
#define FXLDS_U4 4096  // 4*128*8 uint4 = 64 KiB input tile

__global__ __launch_bounds__(256, 1) void conv_fused(
    const float* __restrict__ x,
    const float* __restrict__ wgt,
    float* __restrict__ out)
{
    __shared__ uint4 lds[WLDS_U4 + FXLDS_U4];          // 136 KiB
    uint16_t* lds16 = (uint16_t*)lds;

    const int t    = threadIdx.x;
    const int lane = t & 63;
    const int wv   = t >> 6;
    const int n    = lane & 15;
    const int q    = lane >> 4;

    const int d    = blockIdx.x;
    const int orig = (d & 7) * 128 + (d >> 3);
    const int b    = orig >> 6;
    const int h0   = (orig & 63) * 2;

    #pragma unroll
    for (int p = 0; p < 2; ++p) {
        const int a_  = t + 256 * p;
        const int oc  = a_ >> 3;
        const int oct = a_ & 7;
        const float* src = wgt + (size_t)oc * 576 + (size_t)oct * 72;
        f32x4 w4[18];
        #pragma unroll
        for (int j = 0; j < 18; ++j) w4[j] = ((const f32x4*)src)[j];
        const int ch = oct >> 2, qq = oct & 3;
        const int ii = oc >> 4,  nn = oc & 15;
        #pragma unroll
        for (int kk = 0; kk < 9; ++kk) {
            #define WELEM(e) ((uint32_t)f2bf(w4[((e)*9 + kk) >> 2][((e)*9 + kk) & 3]))
            uint4 val;
            val.x = WELEM(0) | (WELEM(1) << 16);
            val.y = WELEM(2) | (WELEM(3) << 16);
            val.z = WELEM(4) | (WELEM(5) << 16);
            val.w = WELEM(6) | (WELEM(7) << 16);
            #undef WELEM
            lds[((kk * 2 + ch) * 4 + ii) * 64 + qq * 16 + nn] = val;
        }
    }

    {
        const int ic    = t >> 2;
        const int w0    = (t & 3) * 32;
        const int jslot = ic >> 3;
        const int esub  = ic & 7;
        #pragma unroll
        for (int r = 0; r < 4; ++r) {
            const int h = h0 - 1 + r;
            if (h < 0 || h >= H_) {
                uint4 z; z.x = z.y = z.z = z.w = 0;
                #pragma unroll
                for (int k = 0; k < 4; ++k)
                    lds[WLDS_U4 + r * 1024 + k * 256 + t] = z;
            } else {
                const float* src =
                    x + (((size_t)(b * C_ + ic)) * H_ + h) * W_ + w0;
                f32x4 v4[8];
                #pragma unroll
                for (int j = 0; j < 8; ++j) v4[j] = ((const f32x4*)src)[j];
                #pragma unroll
                for (int k = 0; k < 32; ++k) {
                    const int c    = w0 + k;
                    const int slot = (jslot + c) & 7;
                    lds16[WLDS_U4 * 8 + ((r * 128 + c) * 8 + slot) * 8 + esub] =
                        f2bf(v4[k >> 2][k & 3]);
                }
            }
        }
    }
    __syncthreads();

    f32x4 acc[4][4];
    #pragma unroll
    for (int i = 0; i < 4; ++i)
        #pragma unroll
        for (int tt = 0; tt < 4; ++tt)
            acc[i][tt] = (f32x4){0.f, 0.f, 0.f, 0.f};

    const int wb = (wv & 1) * 64;
    const uint4* Wl = lds;
    const uint4* Xl = lds + WLDS_U4;
    const bool lz = (wb + n) == 0;
    const bool rz = (wb + n) == 79;
    const bf16x8 zfrag = 0;

    #pragma unroll
    for (int kh = 0; kh < 3; ++kh) {
        const int row = (wv >> 1) + kh;
        #pragma unroll
        for (int kw = 0; kw < 3; ++kw) {
            const int kk = kh * 3 + kw;
            #pragma unroll
            for (int ch = 0; ch < 2; ++ch) {
                bf16x8 a[4], bb[4];
                #pragma unroll
                for (int i = 0; i < 4; ++i)
                    a[i] = __builtin_bit_cast(bf16x8,
                        Wl[((kk * 2 + ch) * 4 + i) * 64 + lane]);
                #pragma unroll
                for (int tt = 0; tt < 4; ++tt) {
                    int c   = wb + tt * 16 + n + kw - 1;
                    int cc  = min(max(c, 0), 127);
                    int idx = (row * 128 + cc) * 8 + ((ch * 4 + q + cc) & 7);
                    bf16x8 v = __builtin_bit_cast(bf16x8, Xl[idx]);
                    if (kw == 0 && tt == 0) v = lz ? zfrag : v;
                    if (kw == 2 && tt == 3) v = rz ? zfrag : v;
                    bb[tt] = v;
                }
                #pragma unroll
                for (int i = 0; i < 4; ++i)
                    #pragma unroll
                    for (int tt = 0; tt < 4; ++tt)
                        acc[i][tt] = __builtin_amdgcn_mfma_f32_16x16x32_bf16(
                            a[i], bb[tt], acc[i][tt], 0, 0, 0);
            }
        }
    }

    const int  h  = h0 + (wv >> 1);
    const bool hz = (h >= 44 && h < 84);
    #pragma unroll
    for (int i = 0; i < 4; ++i) {
        #pragma unroll
        for (int tt = 0; tt < 4; ++tt) {
            const int  w0 = wb + tt * 16 + n;
            const bool zz = hz && (w0 >= 44 && w0 < 84);
            #pragma unroll
            for (int r = 0; r < 4; ++r) {
                const int oc = i * 16 + q * 4 + r;
                out[(((size_t)b * C_ + oc) * H_ + h) * W_ + w0] =
                    zz ? 0.f : acc[i][tt][r];
            }
        }
    }
}

extern "C" void kernel_launch(void* const* d_in, const int* in_sizes, int n_in,
                              void* d_out, int out_size, void* d_ws, size_t ws_size,
                              hipStream_t stream) {
    const float* x   = (const float*)d_in[0];
    const float* wgt = (const float*)d_in[1];
    float* out       = (float*)d_out;

    const size_t W_BYTES = 9 * 2 * 4 * 64 * 16;   // 73,728
    if (ws_size >= W_BYTES) {
        uint16_t* Wb = (uint16_t*)d_ws;
        xform_weight<<<dim3(144), dim3(256), 0, stream>>>(wgt, Wb);
        conv_main<<<dim3(2048), dim3(256), 0, stream>>>(
            (const uint4*)Wb, x, out);
    } else {
        conv_fused<<<dim3(1024), dim3(256), 0, stream>>>(x, wgt, out);
    }
}